// Round 14
// baseline (384.061 us; speedup 1.0000x reference)
//
#include <hip/hip_runtime.h>

#define B_  32
#define C_  128
#define CS  64
#define H_  64
#define W_  64
#define HW  (H_*W_)

typedef __attribute__((ext_vector_type(8))) short bf16x8_t;
typedef __attribute__((ext_vector_type(4))) float f32x4_t;
typedef unsigned short u16;
typedef unsigned int   u32;

__device__ __forceinline__ float silu_f(float v) { return v / (1.f + __expf(-v)); }

__device__ __forceinline__ u16 f2bf(float f) {
    u32 u = __float_as_uint(f);
    u = (u + 0x7FFFu + ((u >> 16) & 1u)) >> 16;   // RNE
    return (u16)u;
}
__device__ __forceinline__ float bf2f(u16 u) {
    return __uint_as_float(((u32)u) << 16);
}
// one-instruction RNE pack of 2 floats -> 2 bf16 (lo = a, hi = b)
__device__ __forceinline__ u32 cvtpk(float a, float b) {
    u32 r;
    asm("v_cvt_pk_bf16_f32 %0, %1, %2" : "=v"(r) : "v"(a), "v"(b));
    return r;
}

__device__ __forceinline__ void get_coeffs(const float* __restrict__ wts,
                                           const int* __restrict__ idxs, int b,
                                           float& c0, float& c1, float& c2, float& cid) {
    int   i0 = idxs[b*2+0], i1 = idxs[b*2+1];
    float w0 = wts[b*2+0],  w1 = wts[b*2+1];
    c0  = (i0==0?w0:0.f)   + (i1==0?w1:0.f);
    c1  = (i0==1?w0:0.f)   + (i1==1?w1:0.f);
    c2  = (i0==2?w0:0.f)   + (i1==2?w1:0.f);
    cid = (i0==3?0.1f:0.f) + (i1==3?0.1f:0.f);
}

// ---- weight prep + work-list build -------------------------------------------
// wl[0] = work cursor, wl[1] = n_items, wl[2..] = items (tp<<12 | b<<5 | band)
__global__ __launch_bounds__(256) void k_prep(
    const float* __restrict__ e0w, const float* __restrict__ e2aw, const float* __restrict__ e1pw,
    const float* __restrict__ wts, const int* __restrict__ idxs,
    u16* __restrict__ Wt0f, u16* __restrict__ Wt2f, u16* __restrict__ Wt1f,
    u32* __restrict__ wl)
{
    const int i0 = blockIdx.x*256 + threadIdx.x, stride = gridDim.x*256;
    for (int i = i0; i < 73728; i += stride) {
        int j = i&7, lane = (i>>3)&63, cog = (i>>9)&7, kc = (i>>12)&1, tap = i>>13;
        int co = cog*16 + (lane&15), ci = kc*32 + (lane>>4)*8 + j;
        Wt0f[i] = f2bf(e0w[(size_t)(co*64 + ci)*9 + tap]);
    }
    for (int i = i0; i < 73728; i += stride) {
        int j = i&7, lane = (i>>3)&63, cog = (i>>9)&3, kc = (i>>11)&3, tap = i>>13;
        int co = cog*16 + (lane&15), ci = kc*32 + (lane>>4)*8 + j;
        Wt2f[i] = f2bf(e2aw[(size_t)(co*128 + ci)*9 + tap]);
    }
    for (int i = i0; i < 8192; i += stride) {
        int j = i&7, lane = (i>>3)&63, cog = (i>>9)&7, kc = (i>>12)&1;
        int co = cog*16 + (lane&15), ci = kc*32 + (lane>>4)*8 + j;
        Wt1f[i] = f2bf(e1pw[(size_t)co*64 + ci]);
    }

    if (blockIdx.x == 0) {
        __shared__ u32 base[3][32];
        if (threadIdx.x == 0) {
            u32 n = 0;
            for (int tp = 0; tp < 3; ++tp)
                for (int bb = 0; bb < 32; ++bb) {
                    float c0, c1, c2, cid;
                    get_coeffs(wts, idxs, bb, c0, c1, c2, cid);
                    bool act = (tp == 0) ? (c0 != 0.f) : (tp == 1) ? (c2 != 0.f) : (c0 == 0.f);
                    base[tp][bb] = act ? n : 0xFFFFFFFFu;
                    if (act) n += 32;
                }
            wl[0] = 0u;
            wl[1] = n;
        }
        __syncthreads();
        if (threadIdx.x < 32) {
            for (int tp = 0; tp < 3; ++tp)
                for (int bb = 0; bb < 32; ++bb) {
                    u32 bs = base[tp][bb];
                    if (bs != 0xFFFFFFFFu)
                        wl[2 + bs + threadIdx.x] =
                            ((u32)tp << 12) | ((u32)bb << 5) | (u32)threadIdx.x;
                }
        }
    }
}

// ---- stage 4 padded rows x 66 cols x 64 ch from NCHW fp32 -> swizzled bf16 LDS -
__device__ __forceinline__ void stage_x(
    const float* __restrict__ xb,   // x + (b*C + ch0)*HW
    char* lin, int orow0, int t)
{
    f32x4_t V0[8], V1[8];
    #pragma unroll
    for (int k = 0; k < 8; ++k) {
        const int u = t + k*256;
        const int quad = u & 15, r = (u >> 4) & 3, cp = u >> 6;
        const int hh = orow0 - 1 + r;
        const int hcl = (hh < 0) ? 0 : ((hh > 63) ? 63 : hh);
        const float* p0 = xb + (size_t)(2*cp)*HW + hcl*64 + quad*4;
        asm volatile("global_load_dwordx4 %0, %1, off" : "=v"(V0[k]) : "v"(p0));
        asm volatile("global_load_dwordx4 %0, %1, off" : "=v"(V1[k]) : "v"(p0 + HW));
    }
    asm volatile("s_waitcnt vmcnt(0)" ::: "memory");
    __builtin_amdgcn_sched_barrier(0);
    #pragma unroll
    for (int k = 0; k < 8; ++k) {
        const int u = t + k*256;
        const int quad = u & 15, r = (u >> 4) & 3, cp = u >> 6;
        const int hh = orow0 - 1 + r;
        const bool ok = (hh >= 0 && hh < H_);
        #pragma unroll
        for (int j = 0; j < 4; ++j) {
            const int p = r*66 + quad*4 + j + 1;
            const u32 a = ((u32)p*128 + (u32)cp*4) ^ (((u32)(p & 7)) << 4);
            float f0 = ok ? V0[k][j] : 0.f;
            float f1 = ok ? V1[k][j] : 0.f;
            *(u32*)(lin + a) = cvtpk(f0, f1);
        }
    }
    {
        const int cp = t & 31, side = (t >> 5) & 1, r = t >> 6;
        const int p = r*66 + side*65;
        const u32 a = ((u32)p*128 + (u32)cp*4) ^ (((u32)(p & 7)) << 4);
        *(u32*)(lin + a) = 0u;
    }
}

// ---- one K-pass over a staged 64-ch plane, asm A-loads + counted vmcnt --------
template<int NCF, int NPF, int TK, int COUT>
__device__ __forceinline__ void conv_pass(
    const char* lin, const u16* __restrict__ wb, int koff,
    int rbase, int pxbase, int l15, int kg,
    f32x4_t (&acc)[NCF][NPF])
{
    bf16x8_t A0[NCF], A1[NCF], A2[NCF];

    auto issueA = [&](int i, bf16x8_t (&dst)[NCF]) {
        const int tap = i >> 1, kcl = i & 1;
        const u16* wt = wb + (size_t)((tap*TK + koff + kcl)*(COUT/16))*512;
        #pragma unroll
        for (int cf = 0; cf < NCF; ++cf)
            asm volatile("global_load_dwordx4 %0, %1, off"
                         : "=v"(dst[cf]) : "v"(wt + ((size_t)cf << 9)));
    };
    auto ldsB = [&](int i, int pf) -> bf16x8_t {
        const int tap = i >> 1, kcl = i & 1;
        const int dh = tap / 3, dwp = tap % 3;
        const int p = (rbase + dh)*66 + pxbase + pf*16 + l15 + dwp;
        u32 a = (u32)p*128 + (u32)kcl*64 + (u32)kg*16;
        a ^= ((u32)(p & 7)) << 4;
        return *(const bf16x8_t*)(lin + a);
    };

    issueA(0, A0);
    issueA(1, A1);
    #pragma unroll
    for (int i = 0; i < 18; ++i) {
        if (i + 2 < 18) {
            const int s = (i + 2) % 3;
            if (s == 0)      issueA(i + 2, A0);
            else if (s == 1) issueA(i + 2, A1);
            else             issueA(i + 2, A2);
        }
        if (i < 16)       asm volatile("s_waitcnt vmcnt(8)" ::: "memory");
        else if (i == 16) asm volatile("s_waitcnt vmcnt(4)" ::: "memory");
        else              asm volatile("s_waitcnt vmcnt(0)" ::: "memory");
        __builtin_amdgcn_sched_barrier(0);
        bf16x8_t* ac = (i % 3 == 0) ? A0 : ((i % 3 == 1) ? A1 : A2);
        #pragma unroll
        for (int pf = 0; pf < NPF; ++pf) {
            bf16x8_t bfr = ldsB(i, pf);
            #pragma unroll
            for (int cf = 0; cf < NCF; ++cf)
                acc[cf][pf] = __builtin_amdgcn_mfma_f32_16x16x32_bf16(ac[cf], bfr, acc[cf][pf], 0, 0, 0);
        }
    }
}

// ---- persistent conv kernel: 1024 blocks pop items from wl --------------------
__global__ __launch_bounds__(256, 4) void k_conv(
    const float* __restrict__ x,
    const float* __restrict__ wts, const int* __restrict__ idxs,
    const u16* __restrict__ Wt0f, const u16* __restrict__ Wt2f,
    const float* __restrict__ e0g, const float* __restrict__ e0b,
    const float* __restrict__ e0m, const float* __restrict__ e0v,
    const float* __restrict__ e2ag, const float* __restrict__ e2ab,
    const float* __restrict__ e2am, const float* __restrict__ e2av,
    float* __restrict__ out, u16* __restrict__ g1, u32* __restrict__ wl)
{
    __shared__ char lin[33792];
    __shared__ u32 s_item;
    const int t = threadIdx.x;
    const u32 n_items = wl[1];
    const int lane = t & 63, l15 = lane & 15, kg = lane >> 4, wv = t >> 6;

    for (;;) {
        __syncthreads();
        if (t == 0) s_item = atomicAdd(&wl[0], 1u);
        __syncthreads();
        const u32 ii = s_item;
        if (ii >= n_items) return;
        const u32 item = wl[2 + ii];
        const int tp = item >> 12, b = (item >> 5) & 31, band = item & 31;
        const int orow0 = band*2;
        float c0, c1, c2, cid;
        get_coeffs(wts, idxs, b, c0, c1, c2, cid);
        const float* xb = x + (size_t)b*C_*HW;

        if (tp == 2) {   // identity-only init of these 2 rows (all 128 ch)
            for (int i = t; i < 4096; i += 256) {
                int ch = i >> 5, q = i & 31;
                size_t o = ((size_t)(b*C_+ch))*HW + (size_t)orow0*64 + q*4;
                float4 ov;
                if (cid != 0.f) {
                    float4 xv = *(const float4*)(x + o);
                    ov.x = cid*xv.x; ov.y = cid*xv.y; ov.z = cid*xv.z; ov.w = cid*xv.w;
                } else { ov.x = ov.y = ov.z = ov.w = 0.f; }
                *(float4*)(out + o) = ov;
            }
            continue;
        }

        if (tp == 0) {
            stage_x(xb, lin, orow0, t);
            __syncthreads();

            const int cw = wv >> 1, rw = wv & 1;
            const int cobase = cw*64;
            f32x4_t acc[4][4];
            #pragma unroll
            for (int cf = 0; cf < 4; ++cf)
                #pragma unroll
                for (int pf = 0; pf < 4; ++pf)
                    acc[cf][pf] = (f32x4_t){0.f, 0.f, 0.f, 0.f};

            const u16* wb = Wt0f + (size_t)(cobase >> 4)*512 + (size_t)lane*8;
            conv_pass<4, 4, 2, 128>(lin, wb, 0, rw, 0, l15, kg, acc);

            #pragma unroll
            for (int cf = 0; cf < 4; ++cf) {
                float sarr[4], tarr[4];
                #pragma unroll
                for (int r = 0; r < 4; ++r) {
                    int co = cobase + cf*16 + kg*4 + r;
                    float s = e0g[co] * rsqrtf(e0v[co] + 1e-5f);
                    sarr[r] = s; tarr[r] = e0b[co] - e0m[co]*s;
                }
                #pragma unroll
                for (int pf = 0; pf < 4; ++pf) {
                    size_t rowoff = (size_t)(orow0 + rw)*64 + pf*16 + l15;
                    #pragma unroll
                    for (int r = 0; r < 4; ++r) {
                        int co = cobase + cf*16 + kg*4 + r;
                        float v = silu_f(acc[cf][pf][r]*sarr[r] + tarr[r]);
                        size_t o = ((size_t)(b*C_+co))*HW + rowoff;
                        float idv = (cid != 0.f) ? cid*x[o] : 0.f;
                        out[o] = c0*v + idv;
                    }
                }
            }
        } else {
            const int rw = wv >> 1, pw = wv & 1;
            const int pxbase = pw*32;
            f32x4_t acc[4][2];
            #pragma unroll
            for (int cf = 0; cf < 4; ++cf)
                #pragma unroll
                for (int pf = 0; pf < 2; ++pf)
                    acc[cf][pf] = (f32x4_t){0.f, 0.f, 0.f, 0.f};

            const u16* wb = Wt2f + (size_t)lane*8;

            stage_x(xb, lin, orow0, t);
            __syncthreads();
            conv_pass<4, 2, 4, 64>(lin, wb, 0, rw, pxbase, l15, kg, acc);
            __syncthreads();
            stage_x(xb + (size_t)CS*HW, lin, orow0, t);
            __syncthreads();
            conv_pass<4, 2, 4, 64>(lin, wb, 2, rw, pxbase, l15, kg, acc);

            #pragma unroll
            for (int cf = 0; cf < 4; ++cf) {
                float sarr[4], tarr[4];
                #pragma unroll
                for (int r = 0; r < 4; ++r) {
                    int co = cf*16 + kg*4 + r;
                    float s = e2ag[co] * rsqrtf(e2av[co] + 1e-5f);
                    sarr[r] = s; tarr[r] = e2ab[co] - e2am[co]*s;
                }
                #pragma unroll
                for (int pf = 0; pf < 2; ++pf) {
                    size_t rowoff = (size_t)(orow0 + rw)*64 + pxbase + pf*16 + l15;
                    #pragma unroll
                    for (int r = 0; r < 4; ++r) {
                        int co = cf*16 + kg*4 + r;
                        float v = silu_f(acc[cf][pf][r]*sarr[r] + tarr[r]);
                        g1[((size_t)(b*CS+co))*HW + rowoff] = f2bf(v);
                    }
                }
            }
        }
    }
}

// ---- tail: e1 (dw5x5+pw+BN/SiLU, out += c1*e1) then e2b (out += c2*[g1,g2]) ---
__global__ __launch_bounds__(256) void k_tail(
    const float* __restrict__ x, const u16* __restrict__ g1,
    const float* __restrict__ wts, const int* __restrict__ idxs,
    const float* __restrict__ e1dw, const u16* __restrict__ Wt1f,
    const float* __restrict__ e1g, const float* __restrict__ e1b,
    const float* __restrict__ e1m, const float* __restrict__ e1v,
    const float* __restrict__ e2bw,
    const float* __restrict__ e2bg, const float* __restrict__ e2bb,
    const float* __restrict__ e2bm, const float* __restrict__ e2bv,
    float* __restrict__ out)
{
    const int b = blockIdx.y, band = blockIdx.x, t = threadIdx.x;
    const int orow0 = band*2;

    float c0, c1, c2, cid;
    get_coeffs(wts, idxs, b, c0, c1, c2, cid);
    if (c1 == 0.f && c2 == 0.f) return;

    __shared__ u16  lin[6*64*70];
    __shared__ u16  lout[128*72];
    __shared__ float wl[64*26];

    const int lane = t & 63, chl = lane & 15, cs = lane >> 4;
    const int wv = t >> 6, outrow = wv & 1, chhalf = wv >> 1;
    const int l15 = lane & 15, kg = lane >> 4;

    if (c1 != 0.f) {
        for (int i = t; i < 64*25; i += 256) wl[(i/25)*26 + (i%25)] = e1dw[i];
        for (int i = t; i < 6*64*16; i += 256) {
            int q = i & 15, ch = (i >> 4) & 63, r = i >> 10;
            int hh = orow0 - 2 + r;
            u32 w0 = 0u, w1 = 0u;
            if (hh >= 0 && hh < H_) {
                float4 v = *(const float4*)(x + ((size_t)(b*C_ + CS + ch))*HW + hh*64 + q*4);
                w0 = cvtpk(v.x, v.y); w1 = cvtpk(v.z, v.w);
            }
            u32* dst = (u32*)&lin[(r*64 + ch)*70 + 2 + q*4];
            dst[0] = w0; dst[1] = w1;
        }
        for (int i = t; i < 6*64; i += 256) {
            int ch = i & 63, r = i >> 6;
            *(u32*)&lin[(r*64 + ch)*70]      = 0u;
            u32* e = (u32*)&lin[(r*64 + ch)*70 + 66];
            e[0] = 0u; e[1] = 0u;
        }
        __syncthreads();

        #pragma unroll
        for (int chi = 0; chi < 2; ++chi) {
            const int ch = chhalf*32 + chl + chi*16;
            const float* wch = &wl[ch*26];
            float accp[16];
            #pragma unroll
            for (int p = 0; p < 16; ++p) accp[p] = 0.f;
            #pragma unroll
            for (int kh = 0; kh < 5; ++kh) {
                const u16* src = &lin[((outrow + kh)*64 + ch)*70 + cs*16];
                float rb[20];
                #pragma unroll
                for (int k = 0; k < 10; ++k) {
                    u32 u = *(const u32*)(src + 2*k);
                    rb[2*k]   = __uint_as_float(u << 16);
                    rb[2*k+1] = __uint_as_float(u & 0xFFFF0000u);
                }
                #pragma unroll
                for (int kw = 0; kw < 5; ++kw) {
                    float wvv = wch[kh*5 + kw];
                    #pragma unroll
                    for (int p = 0; p < 16; ++p) accp[p] += rb[p+kw]*wvv;
                }
            }
            const int px0 = outrow*64 + cs*16;
            #pragma unroll
            for (int p = 0; p < 16; ++p) lout[(px0+p)*72 + ch] = f2bf(accp[p]);
        }
        __syncthreads();

        const int cw = wv >> 1, pwv = wv & 1;
        f32x4_t acc[4][4];
        #pragma unroll
        for (int cf = 0; cf < 4; ++cf)
            #pragma unroll
            for (int pf = 0; pf < 4; ++pf)
                acc[cf][pf] = (f32x4_t){0.f, 0.f, 0.f, 0.f};

        #pragma unroll
        for (int kc = 0; kc < 2; ++kc) {
            const u16* wt = Wt1f + (((size_t)(kc*8 + cw*4)) << 9) + lane*8;
            bf16x8_t af[4];
            #pragma unroll
            for (int cf = 0; cf < 4; ++cf) af[cf] = *(const bf16x8_t*)(wt + (cf << 9));
            const int k0 = kc*32 + kg*8;
            #pragma unroll
            for (int pf = 0; pf < 4; ++pf) {
                bf16x8_t bfr = *(const bf16x8_t*)&lout[(pwv*64 + pf*16 + l15)*72 + k0];
                #pragma unroll
                for (int cf = 0; cf < 4; ++cf)
                    acc[cf][pf] = __builtin_amdgcn_mfma_f32_16x16x32_bf16(af[cf], bfr, acc[cf][pf], 0, 0, 0);
            }
        }

        #pragma unroll
        for (int cf = 0; cf < 4; ++cf) {
            float sarr[4], tarr[4];
            #pragma unroll
            for (int r = 0; r < 4; ++r) {
                int co = cw*64 + cf*16 + kg*4 + r;
                float s = e1g[co] * rsqrtf(e1v[co] + 1e-5f);
                sarr[r] = s; tarr[r] = e1b[co] - e1m[co]*s;
            }
            #pragma unroll
            for (int pf = 0; pf < 4; ++pf) {
                int px = pwv*64 + pf*16 + l15;
                size_t rowoff = (size_t)(orow0 + (px>>6))*64 + (px&63);
                #pragma unroll
                for (int r = 0; r < 4; ++r) {
                    int co = cw*64 + cf*16 + kg*4 + r;
                    float v = silu_f(acc[cf][pf][r]*sarr[r] + tarr[r]);
                    out[((size_t)(b*C_+co))*HW + rowoff] += c1*v;
                }
            }
        }
    }

    if (c2 != 0.f) {
        __syncthreads();

        for (int i = t; i < 64*25; i += 256) wl[(i/25)*26 + (i%25)] = e2bw[i];
        for (int i = t; i < 6*64*16; i += 256) {
            int q = i & 15, ch = (i >> 4) & 63, r = i >> 10;
            int hh = orow0 - 2 + r;
            u32 w0 = 0u, w1 = 0u;
            if (hh >= 0 && hh < H_) {
                const u32* src = (const u32*)(g1 + ((size_t)(b*CS+ch))*HW + hh*64 + q*4);
                w0 = src[0]; w1 = src[1];
            }
            u32* dst = (u32*)&lin[(r*64 + ch)*70 + 2 + q*4];
            dst[0] = w0; dst[1] = w1;
        }
        for (int i = t; i < 6*64; i += 256) {
            int ch = i & 63, r = i >> 6;
            *(u32*)&lin[(r*64 + ch)*70] = 0u;
            u32* e = (u32*)&lin[(r*64 + ch)*70 + 66];
            e[0] = 0u; e[1] = 0u;
        }
        __syncthreads();

        for (int i = t; i < 2*64*16; i += 256) {
            int q = i & 15, ch = (i >> 4) & 63, r = i >> 10;
            const u16* src = &lin[((r+2)*64 + ch)*70 + 2 + q*4];
            float* op = out + ((size_t)(b*C_+ch))*HW + (size_t)(orow0+r)*64 + q*4;
            float4 ov = *(float4*)op;
            ov.x += c2*bf2f(src[0]); ov.y += c2*bf2f(src[1]);
            ov.z += c2*bf2f(src[2]); ov.w += c2*bf2f(src[3]);
            *(float4*)op = ov;
        }

        #pragma unroll
        for (int chi = 0; chi < 2; ++chi) {
            const int ch = chhalf*32 + chl + chi*16;
            const float* wch = &wl[ch*26];
            float accp[16];
            #pragma unroll
            for (int p = 0; p < 16; ++p) accp[p] = 0.f;
            #pragma unroll
            for (int kh = 0; kh < 5; ++kh) {
                const u16* src = &lin[((outrow + kh)*64 + ch)*70 + cs*16];
                float rb[20];
                #pragma unroll
                for (int k = 0; k < 10; ++k) {
                    u32 u = *(const u32*)(src + 2*k);
                    rb[2*k]   = __uint_as_float(u << 16);
                    rb[2*k+1] = __uint_as_float(u & 0xFFFF0000u);
                }
                #pragma unroll
                for (int kw = 0; kw < 5; ++kw) {
                    float wvv = wch[kh*5 + kw];
                    #pragma unroll
                    for (int p = 0; p < 16; ++p) accp[p] += rb[p+kw]*wvv;
                }
            }
            float s = e2bg[ch] * rsqrtf(e2bv[ch] + 1e-5f);
            float tt = e2bb[ch] - e2bm[ch]*s;
            float* op = out + ((size_t)(b*C_ + CS + ch))*HW + (size_t)(orow0+outrow)*64 + cs*16;
            #pragma unroll
            for (int q = 0; q < 4; ++q) {
                float4 ov = *(float4*)(op + q*4);
                ov.x += c2*silu_f(accp[q*4+0]*s + tt);
                ov.y += c2*silu_f(accp[q*4+1]*s + tt);
                ov.z += c2*silu_f(accp[q*4+2]*s + tt);
                ov.w += c2*silu_f(accp[q*4+3]*s + tt);
                *(float4*)(op + q*4) = ov;
            }
        }
    }
}

extern "C" void kernel_launch(void* const* d_in, const int* in_sizes, int n_in,
                              void* d_out, int out_size, void* d_ws, size_t ws_size,
                              hipStream_t stream) {
    const float* x    = (const float*)d_in[0];
    const float* wts  = (const float*)d_in[1];
    const int*   idxs = (const int*)  d_in[2];
    const float* e0w  = (const float*)d_in[3];
    const float* e0g  = (const float*)d_in[4];
    const float* e0b  = (const float*)d_in[5];
    const float* e0m  = (const float*)d_in[6];
    const float* e0v  = (const float*)d_in[7];
    const float* e1dw = (const float*)d_in[8];
    const float* e1pw = (const float*)d_in[9];
    const float* e1g  = (const float*)d_in[10];
    const float* e1b  = (const float*)d_in[11];
    const float* e1m  = (const float*)d_in[12];
    const float* e1v  = (const float*)d_in[13];
    const float* e2aw = (const float*)d_in[14];
    const float* e2ag = (const float*)d_in[15];
    const float* e2ab = (const float*)d_in[16];
    const float* e2am = (const float*)d_in[17];
    const float* e2av = (const float*)d_in[18];
    const float* e2bw = (const float*)d_in[19];
    const float* e2bg = (const float*)d_in[20];
    const float* e2bb = (const float*)d_in[21];
    const float* e2bm = (const float*)d_in[22];
    const float* e2bv = (const float*)d_in[23];

    float* out = (float*)d_out;

    u16* g1   = (u16*)d_ws;                      // 16.8 MB
    u16* Wt0f = g1 + (size_t)8388608;
    u16* Wt2f = Wt0f + 73728;
    u16* Wt1f = Wt2f + 73728;
    u32* wl   = (u32*)(Wt1f + 8192);             // [cursor, n, items...]

    k_prep<<<128, 256, 0, stream>>>(e0w, e2aw, e1pw, wts, idxs, Wt0f, Wt2f, Wt1f, wl);
    k_conv<<<1024, 256, 0, stream>>>(
        x, wts, idxs, Wt0f, Wt2f,
        e0g, e0b, e0m, e0v, e2ag, e2ab, e2am, e2av, out, g1, wl);
    k_tail<<<dim3(32, B_), 256, 0, stream>>>(
        x, g1, wts, idxs, e1dw, Wt1f, e1g, e1b, e1m, e1v,
        e2bw, e2bg, e2bb, e2bm, e2bv, out);
}

// Round 15
// 91.557 us; speedup vs baseline: 4.1948x; 4.1948x over previous
//
#include <hip/hip_runtime.h>

#define B_  32
#define C_  128
#define CS  64
#define H_  64
#define W_  64
#define HW  (H_*W_)

typedef __attribute__((ext_vector_type(8))) short bf16x8_t;
typedef __attribute__((ext_vector_type(4))) float f32x4_t;
typedef unsigned short u16;
typedef unsigned int   u32;

__device__ __forceinline__ float silu_f(float v) { return v / (1.f + __expf(-v)); }

__device__ __forceinline__ u16 f2bf(float f) {
    u32 u = __float_as_uint(f);
    u = (u + 0x7FFFu + ((u >> 16) & 1u)) >> 16;   // RNE
    return (u16)u;
}
__device__ __forceinline__ float bf2f(u16 u) {
    return __uint_as_float(((u32)u) << 16);
}
// one-instruction RNE pack of 2 floats -> 2 bf16 (lo = a, hi = b)
__device__ __forceinline__ u32 cvtpk(float a, float b) {
    u32 r;
    asm("v_cvt_pk_bf16_f32 %0, %1, %2" : "=v"(r) : "v"(a), "v"(b));
    return r;
}

__device__ __forceinline__ void get_coeffs(const float* __restrict__ wts,
                                           const int* __restrict__ idxs, int b,
                                           float& c0, float& c1, float& c2, float& cid) {
    int   i0 = idxs[b*2+0], i1 = idxs[b*2+1];
    float w0 = wts[b*2+0],  w1 = wts[b*2+1];
    c0  = (i0==0?w0:0.f)   + (i1==0?w1:0.f);
    c1  = (i0==1?w0:0.f)   + (i1==1?w1:0.f);
    c2  = (i0==2?w0:0.f)   + (i1==2?w1:0.f);
    cid = (i0==3?0.1f:0.f) + (i1==3?0.1f:0.f);
}

// ---- weight prep: MFMA-fragment-ordered bf16 weights --------------------------
__global__ __launch_bounds__(256) void k_prep(
    const float* __restrict__ e0w, const float* __restrict__ e2aw, const float* __restrict__ e1pw,
    u16* __restrict__ Wt0f, u16* __restrict__ Wt2f, u16* __restrict__ Wt1f)
{
    const int i0 = blockIdx.x*256 + threadIdx.x, stride = gridDim.x*256;
    for (int i = i0; i < 73728; i += stride) {
        int j = i&7, lane = (i>>3)&63, cog = (i>>9)&7, kc = (i>>12)&1, tap = i>>13;
        int co = cog*16 + (lane&15), ci = kc*32 + (lane>>4)*8 + j;
        Wt0f[i] = f2bf(e0w[(size_t)(co*64 + ci)*9 + tap]);
    }
    for (int i = i0; i < 73728; i += stride) {
        int j = i&7, lane = (i>>3)&63, cog = (i>>9)&3, kc = (i>>11)&3, tap = i>>13;
        int co = cog*16 + (lane&15), ci = kc*32 + (lane>>4)*8 + j;
        Wt2f[i] = f2bf(e2aw[(size_t)(co*128 + ci)*9 + tap]);
    }
    for (int i = i0; i < 8192; i += stride) {
        int j = i&7, lane = (i>>3)&63, cog = (i>>9)&7, kc = (i>>12)&1;
        int co = cog*16 + (lane&15), ci = kc*32 + (lane>>4)*8 + j;
        Wt1f[i] = f2bf(e1pw[(size_t)co*64 + ci]);
    }
}

// ---- stage 4 padded rows x 66 cols x 64 ch from NCHW fp32 -> swizzled bf16 LDS -
__device__ __forceinline__ void stage_x(
    const float* __restrict__ xb,   // x + (b*C + ch0)*HW
    char* lin, int orow0, int t)
{
    f32x4_t V0[8], V1[8];
    #pragma unroll
    for (int k = 0; k < 8; ++k) {
        const int u = t + k*256;
        const int quad = u & 15, r = (u >> 4) & 3, cp = u >> 6;
        const int hh = orow0 - 1 + r;
        const int hcl = (hh < 0) ? 0 : ((hh > 63) ? 63 : hh);
        const float* p0 = xb + (size_t)(2*cp)*HW + hcl*64 + quad*4;
        asm volatile("global_load_dwordx4 %0, %1, off" : "=v"(V0[k]) : "v"(p0));
        asm volatile("global_load_dwordx4 %0, %1, off" : "=v"(V1[k]) : "v"(p0 + HW));
    }
    asm volatile("s_waitcnt vmcnt(0)" ::: "memory");
    __builtin_amdgcn_sched_barrier(0);
    #pragma unroll
    for (int k = 0; k < 8; ++k) {
        const int u = t + k*256;
        const int quad = u & 15, r = (u >> 4) & 3, cp = u >> 6;
        const int hh = orow0 - 1 + r;
        const bool ok = (hh >= 0 && hh < H_);
        #pragma unroll
        for (int j = 0; j < 4; ++j) {
            const int p = r*66 + quad*4 + j + 1;
            const u32 a = ((u32)p*128 + (u32)cp*4) ^ (((u32)(p & 7)) << 4);
            float f0 = ok ? V0[k][j] : 0.f;
            float f1 = ok ? V1[k][j] : 0.f;
            *(u32*)(lin + a) = cvtpk(f0, f1);
        }
    }
    {
        const int cp = t & 31, side = (t >> 5) & 1, r = t >> 6;
        const int p = r*66 + side*65;
        const u32 a = ((u32)p*128 + (u32)cp*4) ^ (((u32)(p & 7)) << 4);
        *(u32*)(lin + a) = 0u;
    }
}

// ---- one K-pass over a staged 64-ch plane, asm A-loads + counted vmcnt --------
template<int NCF, int NPF, int TK, int COUT>
__device__ __forceinline__ void conv_pass(
    const char* lin, const u16* __restrict__ wb, int koff,
    int rbase, int pxbase, int l15, int kg,
    f32x4_t (&acc)[NCF][NPF])
{
    bf16x8_t A0[NCF], A1[NCF], A2[NCF];

    auto issueA = [&](int i, bf16x8_t (&dst)[NCF]) {
        const int tap = i >> 1, kcl = i & 1;
        const u16* wt = wb + (size_t)((tap*TK + koff + kcl)*(COUT/16))*512;
        #pragma unroll
        for (int cf = 0; cf < NCF; ++cf)
            asm volatile("global_load_dwordx4 %0, %1, off"
                         : "=v"(dst[cf]) : "v"(wt + ((size_t)cf << 9)));
    };
    auto ldsB = [&](int i, int pf) -> bf16x8_t {
        const int tap = i >> 1, kcl = i & 1;
        const int dh = tap / 3, dwp = tap % 3;
        const int p = (rbase + dh)*66 + pxbase + pf*16 + l15 + dwp;
        u32 a = (u32)p*128 + (u32)kcl*64 + (u32)kg*16;
        a ^= ((u32)(p & 7)) << 4;
        return *(const bf16x8_t*)(lin + a);
    };

    issueA(0, A0);
    issueA(1, A1);
    #pragma unroll
    for (int i = 0; i < 18; ++i) {
        if (i + 2 < 18) {
            const int s = (i + 2) % 3;
            if (s == 0)      issueA(i + 2, A0);
            else if (s == 1) issueA(i + 2, A1);
            else             issueA(i + 2, A2);
        }
        if (i < 16)       asm volatile("s_waitcnt vmcnt(8)" ::: "memory");
        else if (i == 16) asm volatile("s_waitcnt vmcnt(4)" ::: "memory");
        else              asm volatile("s_waitcnt vmcnt(0)" ::: "memory");
        __builtin_amdgcn_sched_barrier(0);
        bf16x8_t* ac = (i % 3 == 0) ? A0 : ((i % 3 == 1) ? A1 : A2);
        #pragma unroll
        for (int pf = 0; pf < NPF; ++pf) {
            bf16x8_t bfr = ldsB(i, pf);
            #pragma unroll
            for (int cf = 0; cf < NCF; ++cf)
                acc[cf][pf] = __builtin_amdgcn_mfma_f32_16x16x32_bf16(ac[cf], bfr, acc[cf][pf], 0, 0, 0);
        }
    }
}

// ---- merged conv kernel: grid (32 bands, B, 2). z=0: e0+identity+e1. z=1: e2a -
// LDS union 51968 B -> 3 blocks/CU.
__global__ __launch_bounds__(256, 3) void k_conv(
    const float* __restrict__ x,
    const float* __restrict__ wts, const int* __restrict__ idxs,
    const u16* __restrict__ Wt0f, const u16* __restrict__ Wt2f,
    const float* __restrict__ e0g, const float* __restrict__ e0b,
    const float* __restrict__ e0m, const float* __restrict__ e0v,
    const float* __restrict__ e2ag, const float* __restrict__ e2ab,
    const float* __restrict__ e2am, const float* __restrict__ e2av,
    const float* __restrict__ e1dw, const u16* __restrict__ Wt1f,
    const float* __restrict__ e1g, const float* __restrict__ e1b,
    const float* __restrict__ e1m, const float* __restrict__ e1v,
    float* __restrict__ out, u16* __restrict__ g1)
{
    __shared__ char uni[51968];
    const int b = blockIdx.y, orow0 = blockIdx.x*2, t = threadIdx.x;
    float c0, c1, c2, cid;
    get_coeffs(wts, idxs, b, c0, c1, c2, cid);

    const int lane = t & 63, l15 = lane & 15, kg = lane >> 4, wv = t >> 6;
    const float* xb = x + (size_t)b*C_*HW;

    if (blockIdx.z == 1) {
        if (c2 == 0.f) return;

        const int rw = wv >> 1, pw = wv & 1;
        const int pxbase = pw*32;
        f32x4_t acc[4][2];
        #pragma unroll
        for (int cf = 0; cf < 4; ++cf)
            #pragma unroll
            for (int pf = 0; pf < 2; ++pf)
                acc[cf][pf] = (f32x4_t){0.f, 0.f, 0.f, 0.f};

        const u16* wb = Wt2f + (size_t)lane*8;

        stage_x(xb, uni, orow0, t);
        __syncthreads();
        conv_pass<4, 2, 4, 64>(uni, wb, 0, rw, pxbase, l15, kg, acc);
        __syncthreads();
        stage_x(xb + (size_t)CS*HW, uni, orow0, t);
        __syncthreads();
        conv_pass<4, 2, 4, 64>(uni, wb, 2, rw, pxbase, l15, kg, acc);

        #pragma unroll
        for (int cf = 0; cf < 4; ++cf) {
            float sarr[4], tarr[4];
            #pragma unroll
            for (int r = 0; r < 4; ++r) {
                int co = cf*16 + kg*4 + r;
                float s = e2ag[co] * rsqrtf(e2av[co] + 1e-5f);
                sarr[r] = s; tarr[r] = e2ab[co] - e2am[co]*s;
            }
            #pragma unroll
            for (int pf = 0; pf < 2; ++pf) {
                size_t rowoff = (size_t)(orow0 + rw)*64 + pxbase + pf*16 + l15;
                #pragma unroll
                for (int r = 0; r < 4; ++r) {
                    int co = cf*16 + kg*4 + r;
                    float v = silu_f(acc[cf][pf][r]*sarr[r] + tarr[r]);
                    g1[((size_t)(b*CS+co))*HW + rowoff] = f2bf(v);
                }
            }
        }
        return;
    }

    // ---------------- z == 0: e0 / identity, then fused e1 ----------------
    const int cw = wv >> 1, rw = wv & 1;
    const int cobase = cw*64;

    if (c0 != 0.f) {
        stage_x(xb, uni, orow0, t);
        __syncthreads();

        f32x4_t acc[4][4];
        #pragma unroll
        for (int cf = 0; cf < 4; ++cf)
            #pragma unroll
            for (int pf = 0; pf < 4; ++pf)
                acc[cf][pf] = (f32x4_t){0.f, 0.f, 0.f, 0.f};

        const u16* wb = Wt0f + (size_t)(cobase >> 4)*512 + (size_t)lane*8;
        conv_pass<4, 4, 2, 128>(uni, wb, 0, rw, 0, l15, kg, acc);

        #pragma unroll
        for (int cf = 0; cf < 4; ++cf) {
            float sarr[4], tarr[4];
            #pragma unroll
            for (int r = 0; r < 4; ++r) {
                int co = cobase + cf*16 + kg*4 + r;
                float s = e0g[co] * rsqrtf(e0v[co] + 1e-5f);
                sarr[r] = s; tarr[r] = e0b[co] - e0m[co]*s;
            }
            #pragma unroll
            for (int pf = 0; pf < 4; ++pf) {
                size_t rowoff = (size_t)(orow0 + rw)*64 + pf*16 + l15;
                #pragma unroll
                for (int r = 0; r < 4; ++r) {
                    int co = cobase + cf*16 + kg*4 + r;
                    float v = silu_f(acc[cf][pf][r]*sarr[r] + tarr[r]);
                    size_t o = ((size_t)(b*C_+co))*HW + rowoff;
                    float idv = (cid != 0.f) ? cid*x[o] : 0.f;
                    out[o] = c0*v + idv;
                }
            }
        }
    } else if (c1 == 0.f) {
        // identity-only fast path (float4), no e1 to fuse
        for (int i = t; i < 4096; i += 256) {
            int ch = i >> 5, q = i & 31;
            size_t o = ((size_t)(b*C_+ch))*HW + (size_t)orow0*64 + q*4;
            float4 ov;
            if (cid != 0.f) {
                float4 xv = *(const float4*)(x + o);
                ov.x = cid*xv.x; ov.y = cid*xv.y; ov.z = cid*xv.z; ov.w = cid*xv.w;
            } else { ov.x = ov.y = ov.z = ov.w = 0.f; }
            *(float4*)(out + o) = ov;
        }
        return;
    } else {
        // identity init with e0-epilogue ownership (same-thread RMW for e1)
        #pragma unroll
        for (int cf = 0; cf < 4; ++cf)
            #pragma unroll
            for (int pf = 0; pf < 4; ++pf) {
                size_t rowoff = (size_t)(orow0 + rw)*64 + pf*16 + l15;
                #pragma unroll
                for (int r = 0; r < 4; ++r) {
                    int co = cobase + cf*16 + kg*4 + r;
                    size_t o = ((size_t)(b*C_+co))*HW + rowoff;
                    out[o] = (cid != 0.f) ? cid*x[o] : 0.f;
                }
            }
    }

    if (c1 == 0.f) return;

    // ---------------- fused e1: dw5x5 (2x 32-ch passes) -> pw MFMA -> out += ---
    u16*   lin2 = (u16*)uni;                 // [6][32][70] u16 = 26880 B
    u16*   lout = (u16*)(uni + 26880);       // [128][72] u16 = 18432 B
    float* wlf  = (float*)(uni + 45312);     // [64][26] = 6656 B

    __syncthreads();   // conv-phase LDS reads done before re-use
    for (int i = t; i < 64*25; i += 256) wlf[(i/25)*26 + (i%25)] = e1dw[i];

    #pragma unroll
    for (int pass = 0; pass < 2; ++pass) {
        if (pass) __syncthreads();   // dw reads of pass 0 done before restage
        for (int i = t; i < 6*32*16; i += 256) {
            int q = i & 15, chs = (i >> 4) & 31, r = i >> 9;
            int hh = orow0 - 2 + r;
            u32 w0 = 0u, w1 = 0u;
            if (hh >= 0 && hh < H_) {
                float4 v = *(const float4*)(x + ((size_t)(b*C_ + CS + pass*32 + chs))*HW + hh*64 + q*4);
                w0 = cvtpk(v.x, v.y); w1 = cvtpk(v.z, v.w);
            }
            u32* dst = (u32*)&lin2[(r*32 + chs)*70 + 2 + q*4];
            dst[0] = w0; dst[1] = w1;
        }
        for (int i = t; i < 6*32; i += 256) {
            int chs = i & 31, r = i >> 5;
            *(u32*)&lin2[(r*32 + chs)*70] = 0u;
            u32* e = (u32*)&lin2[(r*32 + chs)*70 + 66];
            e[0] = 0u; e[1] = 0u;
        }
        __syncthreads();

        // dw: wave wv -> (outrow = wv&1, cgrp = wv>>1); 16 ch x 64 px per wave
        {
            const int outrow = wv & 1, cgrp = wv >> 1;
            const int chloc = cgrp*16 + l15, cs_ = kg;
            const float* wch = &wlf[(pass*32 + chloc)*26];
            float accp[16];
            #pragma unroll
            for (int p = 0; p < 16; ++p) accp[p] = 0.f;
            #pragma unroll
            for (int kh = 0; kh < 5; ++kh) {
                const u16* src = &lin2[((outrow + kh)*32 + chloc)*70 + cs_*16];
                float rb[20];
                #pragma unroll
                for (int k = 0; k < 10; ++k) {
                    u32 u = *(const u32*)(src + 2*k);
                    rb[2*k]   = __uint_as_float(u << 16);
                    rb[2*k+1] = __uint_as_float(u & 0xFFFF0000u);
                }
                #pragma unroll
                for (int kw = 0; kw < 5; ++kw) {
                    float wvv = wch[kh*5 + kw];
                    #pragma unroll
                    for (int p = 0; p < 16; ++p) accp[p] += rb[p+kw]*wvv;
                }
            }
            const int px0 = outrow*64 + cs_*16;
            #pragma unroll
            for (int p = 0; p < 16; ++p)
                lout[(px0+p)*72 + pass*32 + chloc] = f2bf(accp[p]);
        }
    }
    __syncthreads();

    // pw MFMA + BN/SiLU: out += c1*e1  (ownership identical to e0 epilogue)
    {
        const int pwv = rw;   // same wave decomposition
        f32x4_t acc1[4][4];
        #pragma unroll
        for (int cf = 0; cf < 4; ++cf)
            #pragma unroll
            for (int pf = 0; pf < 4; ++pf)
                acc1[cf][pf] = (f32x4_t){0.f, 0.f, 0.f, 0.f};

        #pragma unroll
        for (int kc = 0; kc < 2; ++kc) {
            const u16* wt = Wt1f + (((size_t)(kc*8 + cw*4)) << 9) + lane*8;
            bf16x8_t af[4];
            #pragma unroll
            for (int cf = 0; cf < 4; ++cf) af[cf] = *(const bf16x8_t*)(wt + (cf << 9));
            const int k0 = kc*32 + kg*8;
            #pragma unroll
            for (int pf = 0; pf < 4; ++pf) {
                bf16x8_t bfr = *(const bf16x8_t*)&lout[(pwv*64 + pf*16 + l15)*72 + k0];
                #pragma unroll
                for (int cf = 0; cf < 4; ++cf)
                    acc1[cf][pf] = __builtin_amdgcn_mfma_f32_16x16x32_bf16(af[cf], bfr, acc1[cf][pf], 0, 0, 0);
            }
        }

        #pragma unroll
        for (int cf = 0; cf < 4; ++cf) {
            float sarr[4], tarr[4];
            #pragma unroll
            for (int r = 0; r < 4; ++r) {
                int co = cw*64 + cf*16 + kg*4 + r;
                float s = e1g[co] * rsqrtf(e1v[co] + 1e-5f);
                sarr[r] = s; tarr[r] = e1b[co] - e1m[co]*s;
            }
            #pragma unroll
            for (int pf = 0; pf < 4; ++pf) {
                size_t rowoff = (size_t)(orow0 + pwv)*64 + pf*16 + l15;
                #pragma unroll
                for (int r = 0; r < 4; ++r) {
                    int co = cw*64 + cf*16 + kg*4 + r;
                    float v = silu_f(acc1[cf][pf][r]*sarr[r] + tarr[r]);
                    out[((size_t)(b*C_+co))*HW + rowoff] += c1*v;
                }
            }
        }
    }
}

// ---- e2b: out[:, :64] += c2*g1 ; out[:, 64:] += c2*silu(bn(dw5x5(g1))) --------
__global__ __launch_bounds__(256) void k_e2b(
    const u16* __restrict__ g1, const float* __restrict__ wts, const int* __restrict__ idxs,
    const float* __restrict__ dww, const float* __restrict__ gg, const float* __restrict__ bb,
    const float* __restrict__ mm, const float* __restrict__ vv, float* __restrict__ out)
{
    const int b = blockIdx.y, band = blockIdx.x, t = threadIdx.x;
    const int orow0 = band*2;

    float c0, c1, c2, cid;
    get_coeffs(wts, idxs, b, c0, c1, c2, cid);
    if (c2 == 0.f) return;

    __shared__ u16  lin[6*64*70];
    __shared__ float wl[64*26];

    for (int i = t; i < 64*25; i += 256) wl[(i/25)*26 + (i%25)] = dww[i];
    for (int i = t; i < 6*64*16; i += 256) {
        int q = i & 15, ch = (i >> 4) & 63, r = i >> 10;
        int hh = orow0 - 2 + r;
        u32 w0 = 0u, w1 = 0u;
        if (hh >= 0 && hh < H_) {
            const u32* src = (const u32*)(g1 + ((size_t)(b*CS+ch))*HW + hh*64 + q*4);
            w0 = src[0]; w1 = src[1];
        }
        u32* dst = (u32*)&lin[(r*64 + ch)*70 + 2 + q*4];
        dst[0] = w0; dst[1] = w1;
    }
    for (int i = t; i < 6*64; i += 256) {
        int ch = i & 63, r = i >> 6;
        *(u32*)&lin[(r*64 + ch)*70] = 0u;
        u32* e = (u32*)&lin[(r*64 + ch)*70 + 66];
        e[0] = 0u; e[1] = 0u;
    }
    __syncthreads();

    // out[:, :64] += c2*g1 for the 2 center rows (lin rows 2,3)
    for (int i = t; i < 2*64*16; i += 256) {
        int q = i & 15, ch = (i >> 4) & 63, r = i >> 10;
        const u16* src = &lin[((r+2)*64 + ch)*70 + 2 + q*4];
        float* op = out + ((size_t)(b*C_+ch))*HW + (size_t)(orow0+r)*64 + q*4;
        float4 ov = *(float4*)op;
        ov.x += c2*bf2f(src[0]); ov.y += c2*bf2f(src[1]);
        ov.z += c2*bf2f(src[2]); ov.w += c2*bf2f(src[3]);
        *(float4*)op = ov;
    }

    const int lane = t & 63, chl = lane & 15, cs = lane >> 4;
    const int wv = t >> 6, outrow = wv & 1, chhalf = wv >> 1;

    #pragma unroll
    for (int chi = 0; chi < 2; ++chi) {
        const int ch = chhalf*32 + chl + chi*16;
        const float* wch = &wl[ch*26];
        float accp[16];
        #pragma unroll
        for (int p = 0; p < 16; ++p) accp[p] = 0.f;
        #pragma unroll
        for (int kh = 0; kh < 5; ++kh) {
            const u16* src = &lin[((outrow + kh)*64 + ch)*70 + cs*16];
            float rb[20];
            #pragma unroll
            for (int k = 0; k < 10; ++k) {
                u32 u = *(const u32*)(src + 2*k);
                rb[2*k]   = __uint_as_float(u << 16);
                rb[2*k+1] = __uint_as_float(u & 0xFFFF0000u);
            }
            #pragma unroll
            for (int kw = 0; kw < 5; ++kw) {
                float wvv = wch[kh*5 + kw];
                #pragma unroll
                for (int p = 0; p < 16; ++p) accp[p] += rb[p+kw]*wvv;
            }
        }
        float s = gg[ch] * rsqrtf(vv[ch] + 1e-5f);
        float tt = bb[ch] - mm[ch]*s;
        float* op = out + ((size_t)(b*C_ + CS + ch))*HW + (size_t)(orow0+outrow)*64 + cs*16;
        #pragma unroll
        for (int q = 0; q < 4; ++q) {
            float4 ov = *(float4*)(op + q*4);
            ov.x += c2*silu_f(accp[q*4+0]*s + tt);
            ov.y += c2*silu_f(accp[q*4+1]*s + tt);
            ov.z += c2*silu_f(accp[q*4+2]*s + tt);
            ov.w += c2*silu_f(accp[q*4+3]*s + tt);
            *(float4*)(op + q*4) = ov;
        }
    }
}

extern "C" void kernel_launch(void* const* d_in, const int* in_sizes, int n_in,
                              void* d_out, int out_size, void* d_ws, size_t ws_size,
                              hipStream_t stream) {
    const float* x    = (const float*)d_in[0];
    const float* wts  = (const float*)d_in[1];
    const int*   idxs = (const int*)  d_in[2];
    const float* e0w  = (const float*)d_in[3];
    const float* e0g  = (const float*)d_in[4];
    const float* e0b  = (const float*)d_in[5];
    const float* e0m  = (const float*)d_in[6];
    const float* e0v  = (const float*)d_in[7];
    const float* e1dw = (const float*)d_in[8];
    const float* e1pw = (const float*)d_in[9];
    const float* e1g  = (const float*)d_in[10];
    const float* e1b  = (const float*)d_in[11];
    const float* e1m  = (const float*)d_in[12];
    const float* e1v  = (const float*)d_in[13];
    const float* e2aw = (const float*)d_in[14];
    const float* e2ag = (const float*)d_in[15];
    const float* e2ab = (const float*)d_in[16];
    const float* e2am = (const float*)d_in[17];
    const float* e2av = (const float*)d_in[18];
    const float* e2bw = (const float*)d_in[19];
    const float* e2bg = (const float*)d_in[20];
    const float* e2bb = (const float*)d_in[21];
    const float* e2bm = (const float*)d_in[22];
    const float* e2bv = (const float*)d_in[23];

    float* out = (float*)d_out;

    u16* g1   = (u16*)d_ws;                      // 16.8 MB
    u16* Wt0f = g1 + (size_t)8388608;
    u16* Wt2f = Wt0f + 73728;
    u16* Wt1f = Wt2f + 73728;

    k_prep<<<128, 256, 0, stream>>>(e0w, e2aw, e1pw, Wt0f, Wt2f, Wt1f);
    k_conv<<<dim3(32, B_, 2), 256, 0, stream>>>(
        x, wts, idxs, Wt0f, Wt2f,
        e0g, e0b, e0m, e0v, e2ag, e2ab, e2am, e2av,
        e1dw, Wt1f, e1g, e1b, e1m, e1v, out, g1);
    k_e2b<<<dim3(32, B_), 256, 0, stream>>>(
        g1, wts, idxs, e2bw, e2bg, e2bb, e2bm, e2bv, out);
}